// Round 1
// baseline (11018.280 us; speedup 1.0000x reference)
//
#include <hip/hip_runtime.h>
#include <hip/hip_bf16.h>
#include <cstdint>
#include <cstddef>

// 3-layer LSTM: T=128, B=256, IN=512, H1=H2=1024, H3=512.
// Strategy (round 0 baseline):
//   - pack weights to bf16 [N][K1+K2] once per launch (ws re-poisoned each call)
//   - per step, per layer: fused-K MFMA GEMM (gates, fp32) + elementwise cell kernel
//   - h kept in bf16 (GEMM A operand) and fp32 (final output); c in fp32

typedef __attribute__((ext_vector_type(8))) short short8;
typedef __attribute__((ext_vector_type(4))) float floatx4;

#define B_ 256
#define T_ 128
#define IN_ 512
#define H1_ 1024
#define H2_ 1024
#define H3_ 512

// ---------------- pack / convert kernels ----------------

__global__ void pack_weights_kernel(const float* __restrict__ Wih,
                                    const float* __restrict__ Whh,
                                    int K1, int K2, int N,
                                    __hip_bfloat16* __restrict__ Wp) {
    int Ktot = K1 + K2;
    int idx = blockIdx.x * 256 + threadIdx.x;
    int total = N * Ktot;
    if (idx >= total) return;
    int j = idx / Ktot;
    int k = idx - j * Ktot;
    float v = (k < K1) ? Wih[(size_t)j * K1 + k] : Whh[(size_t)j * K2 + (k - K1)];
    Wp[idx] = __float2bfloat16(v);
}

__global__ void pack_bias_kernel(const float* __restrict__ a,
                                 const float* __restrict__ b,
                                 int n, float* __restrict__ out) {
    int i = blockIdx.x * 256 + threadIdx.x;
    if (i < n) out[i] = a[i] + b[i];
}

__global__ void f32_to_bf16_kernel(const float* __restrict__ in,
                                   __hip_bfloat16* __restrict__ out, int n) {
    int i = blockIdx.x * 256 + threadIdx.x;
    if (i < n) out[i] = __float2bfloat16(in[i]);
}

__global__ void zero_bf16_kernel(__hip_bfloat16* p, int n) {
    int i = blockIdx.x * 256 + threadIdx.x;
    if (i < n) p[i] = __float2bfloat16(0.f);
}

__global__ void zero_f32_kernel(float* p, int n) {
    int i = blockIdx.x * 256 + threadIdx.x;
    if (i < n) p[i] = 0.f;
}

// ---------------- GEMM: gates = [A1|A2] @ W^T + bias ----------------
// C tile 64x64 per block, 4 waves, each wave 32x32 via 2x2 mfma_f32_16x16x32_bf16.
// A = concat(A1[K1], A2[K2]) along K, both bf16 row-major. W bf16 [N][Ktot].
__launch_bounds__(256)
__global__ void gates_gemm_kernel(const __hip_bfloat16* __restrict__ A1, int K1, int lda1,
                                  const __hip_bfloat16* __restrict__ A2, int lda2,
                                  const __hip_bfloat16* __restrict__ W,
                                  const float* __restrict__ bias,
                                  float* __restrict__ gates,
                                  int N, int Ktot) {
    __shared__ __hip_bfloat16 Asm[64 * 32];
    __shared__ __hip_bfloat16 Bsm[64 * 32];
    const int tid  = threadIdx.x;
    const int lane = tid & 63;
    const int wave = tid >> 6;
    const int row0 = blockIdx.y * 64;   // batch rows
    const int col0 = blockIdx.x * 64;   // gate cols
    const int sr = tid >> 2;            // staging row 0..63
    const int sc = (tid & 3) * 8;       // staging col (elements)

    floatx4 acc[2][2];
#pragma unroll
    for (int i = 0; i < 2; ++i)
#pragma unroll
        for (int j = 0; j < 2; ++j)
            acc[i][j] = (floatx4){0.f, 0.f, 0.f, 0.f};

    const int wr = (wave >> 1) * 32;    // wave row offset in tile
    const int wc = (wave & 1) * 32;     // wave col offset in tile
    const int fr = lane & 15;
    const int fk = (lane >> 4) * 8;

    const int nk = Ktot / 32;
    for (int kc = 0; kc < nk; ++kc) {
        const int k0 = kc * 32;
        const __hip_bfloat16* aptr =
            (k0 < K1) ? (A1 + (size_t)(row0 + sr) * lda1 + k0 + sc)
                      : (A2 + (size_t)(row0 + sr) * lda2 + (k0 - K1) + sc);
        short8 av = *(const short8*)aptr;
        short8 bv = *(const short8*)(W + (size_t)(col0 + sr) * Ktot + k0 + sc);
        __syncthreads();
        *(short8*)(Asm + tid * 8) = av;   // flat idx == sr*32 + sc
        *(short8*)(Bsm + tid * 8) = bv;
        __syncthreads();
        short8 a0 = *(const short8*)(Asm + (wr + fr) * 32 + fk);
        short8 a1 = *(const short8*)(Asm + (wr + 16 + fr) * 32 + fk);
        short8 b0 = *(const short8*)(Bsm + (wc + fr) * 32 + fk);
        short8 b1 = *(const short8*)(Bsm + (wc + 16 + fr) * 32 + fk);
        acc[0][0] = __builtin_amdgcn_mfma_f32_16x16x32_bf16(a0, b0, acc[0][0], 0, 0, 0);
        acc[0][1] = __builtin_amdgcn_mfma_f32_16x16x32_bf16(a0, b1, acc[0][1], 0, 0, 0);
        acc[1][0] = __builtin_amdgcn_mfma_f32_16x16x32_bf16(a1, b0, acc[1][0], 0, 0, 0);
        acc[1][1] = __builtin_amdgcn_mfma_f32_16x16x32_bf16(a1, b1, acc[1][1], 0, 0, 0);
    }

    // epilogue: C/D layout col=lane&15, row=(lane>>4)*4+reg
    const int cn_ = lane & 15;
    const int rb  = (lane >> 4) * 4;
#pragma unroll
    for (int mi = 0; mi < 2; ++mi) {
#pragma unroll
        for (int ni = 0; ni < 2; ++ni) {
            int col = col0 + wc + ni * 16 + cn_;
            float bv = bias[col];
#pragma unroll
            for (int r = 0; r < 4; ++r) {
                int row = row0 + wr + mi * 16 + rb + r;
                gates[(size_t)row * N + col] = acc[mi][ni][r] + bv;
            }
        }
    }
}

// ---------------- LSTM cell elementwise ----------------
__global__ void lstm_cell_kernel(const float* __restrict__ gates, int H,
                                 float* __restrict__ c,
                                 __hip_bfloat16* __restrict__ hb,
                                 float* __restrict__ hf) {
    int j = blockIdx.x * 256 + threadIdx.x;   // hidden index
    int b = blockIdx.y;                        // batch index
    const float* g = gates + (size_t)b * 4 * H;
    float xi = g[j];
    float xf = g[H + j];
    float xg = g[2 * H + j];
    float xo = g[3 * H + j];
    float i_ = 1.f / (1.f + expf(-xi));
    float f_ = 1.f / (1.f + expf(-xf));
    float g_ = tanhf(xg);
    float o_ = 1.f / (1.f + expf(-xo));
    size_t idx = (size_t)b * H + j;
    float cn = f_ * c[idx] + i_ * g_;
    c[idx] = cn;
    float hn = o_ * tanhf(cn);
    hb[idx] = __float2bfloat16(hn);
    hf[idx] = hn;
}

// ---------------- finalize ----------------
__global__ void copy_f32_kernel(const float* __restrict__ src, float* __restrict__ dst, int n) {
    int i = blockIdx.x * 256 + threadIdx.x;
    if (i < n) dst[i] = src[i];
}

extern "C" void kernel_launch(void* const* d_in, const int* in_sizes, int n_in,
                              void* d_out, int out_size, void* d_ws, size_t ws_size,
                              hipStream_t stream) {
    const float* x    = (const float*)d_in[0];
    const float* Wih1 = (const float*)d_in[1];
    const float* Whh1 = (const float*)d_in[2];
    const float* bih1 = (const float*)d_in[3];
    const float* bhh1 = (const float*)d_in[4];
    const float* Wih2 = (const float*)d_in[5];
    const float* Whh2 = (const float*)d_in[6];
    const float* bih2 = (const float*)d_in[7];
    const float* bhh2 = (const float*)d_in[8];
    const float* Wih3 = (const float*)d_in[9];
    const float* Whh3 = (const float*)d_in[10];
    const float* bih3 = (const float*)d_in[11];
    const float* bhh3 = (const float*)d_in[12];
    float* out = (float*)d_out;

    // ---- workspace layout ----
    char* p = (char*)d_ws;
    auto alloc = [&](size_t bytes) {
        char* r = p;
        p += (bytes + 255) & ~(size_t)255;
        return r;
    };
    __hip_bfloat16* xb  = (__hip_bfloat16*)alloc((size_t)T_ * B_ * IN_ * 2);
    __hip_bfloat16* W1p = (__hip_bfloat16*)alloc((size_t)4 * H1_ * (IN_ + H1_) * 2);
    __hip_bfloat16* W2p = (__hip_bfloat16*)alloc((size_t)4 * H2_ * (H1_ + H2_) * 2);
    __hip_bfloat16* W3p = (__hip_bfloat16*)alloc((size_t)4 * H3_ * (H2_ + H3_) * 2);
    float* b1 = (float*)alloc(4 * H1_ * 4);
    float* b2 = (float*)alloc(4 * H2_ * 4);
    float* b3 = (float*)alloc(4 * H3_ * 4);
    __hip_bfloat16* h1b = (__hip_bfloat16*)alloc((size_t)B_ * H1_ * 2);
    __hip_bfloat16* h2b = (__hip_bfloat16*)alloc((size_t)B_ * H2_ * 2);
    __hip_bfloat16* h3b = (__hip_bfloat16*)alloc((size_t)B_ * H3_ * 2);
    float* h1f = (float*)alloc((size_t)B_ * H1_ * 4);
    float* h2f = (float*)alloc((size_t)B_ * H2_ * 4);
    float* h3f = (float*)alloc((size_t)B_ * H3_ * 4);
    float* c1  = (float*)alloc((size_t)B_ * H1_ * 4);
    float* c2  = (float*)alloc((size_t)B_ * H2_ * 4);
    float* c3  = (float*)alloc((size_t)B_ * H3_ * 4);
    float* gates = (float*)alloc((size_t)B_ * 4 * H1_ * 4);

    auto blocks = [](int n) { return (n + 255) / 256; };

    // ---- pack weights / biases, convert x, zero state ----
    pack_weights_kernel<<<blocks(4 * H1_ * (IN_ + H1_)), 256, 0, stream>>>(Wih1, Whh1, IN_, H1_, 4 * H1_, W1p);
    pack_weights_kernel<<<blocks(4 * H2_ * (H1_ + H2_)), 256, 0, stream>>>(Wih2, Whh2, H1_, H2_, 4 * H2_, W2p);
    pack_weights_kernel<<<blocks(4 * H3_ * (H2_ + H3_)), 256, 0, stream>>>(Wih3, Whh3, H2_, H3_, 4 * H3_, W3p);
    pack_bias_kernel<<<blocks(4 * H1_), 256, 0, stream>>>(bih1, bhh1, 4 * H1_, b1);
    pack_bias_kernel<<<blocks(4 * H2_), 256, 0, stream>>>(bih2, bhh2, 4 * H2_, b2);
    pack_bias_kernel<<<blocks(4 * H3_), 256, 0, stream>>>(bih3, bhh3, 4 * H3_, b3);
    f32_to_bf16_kernel<<<blocks(T_ * B_ * IN_), 256, 0, stream>>>(x, xb, T_ * B_ * IN_);
    zero_bf16_kernel<<<blocks(B_ * H1_), 256, 0, stream>>>(h1b, B_ * H1_);
    zero_bf16_kernel<<<blocks(B_ * H2_), 256, 0, stream>>>(h2b, B_ * H2_);
    zero_bf16_kernel<<<blocks(B_ * H3_), 256, 0, stream>>>(h3b, B_ * H3_);
    zero_f32_kernel<<<blocks(B_ * H1_), 256, 0, stream>>>(c1, B_ * H1_);
    zero_f32_kernel<<<blocks(B_ * H2_), 256, 0, stream>>>(c2, B_ * H2_);
    zero_f32_kernel<<<blocks(B_ * H3_), 256, 0, stream>>>(c3, B_ * H3_);

    // ---- time loop ----
    for (int t = 0; t < T_; ++t) {
        const __hip_bfloat16* xt = xb + (size_t)t * B_ * IN_;
        // layer 1: gates = [x_t | h1] @ W1p^T + b1
        gates_gemm_kernel<<<dim3(4 * H1_ / 64, B_ / 64), 256, 0, stream>>>(
            xt, IN_, IN_, h1b, H1_, W1p, b1, gates, 4 * H1_, IN_ + H1_);
        lstm_cell_kernel<<<dim3(H1_ / 256, B_), 256, 0, stream>>>(gates, H1_, c1, h1b, h1f);
        // layer 2: gates = [h1 | h2] @ W2p^T + b2
        gates_gemm_kernel<<<dim3(4 * H2_ / 64, B_ / 64), 256, 0, stream>>>(
            h1b, H1_, H1_, h2b, H2_, W2p, b2, gates, 4 * H2_, H1_ + H2_);
        lstm_cell_kernel<<<dim3(H2_ / 256, B_), 256, 0, stream>>>(gates, H2_, c2, h2b, h2f);
        // layer 3: gates = [h2 | h3] @ W3p^T + b3
        gates_gemm_kernel<<<dim3(4 * H3_ / 64, B_ / 64), 256, 0, stream>>>(
            h2b, H2_, H2_, h3b, H3_, W3p, b3, gates, 4 * H3_, H2_ + H3_);
        lstm_cell_kernel<<<dim3(H3_ / 256, B_), 256, 0, stream>>>(gates, H3_, c3, h3b, h3f);
    }

    // ---- finalize: d_out = [h1, c1, h2, c2, h3, c3] fp32 ----
    size_t o = 0;
    copy_f32_kernel<<<blocks(B_ * H1_), 256, 0, stream>>>(h1f, out + o, B_ * H1_); o += B_ * H1_;
    copy_f32_kernel<<<blocks(B_ * H1_), 256, 0, stream>>>(c1,  out + o, B_ * H1_); o += B_ * H1_;
    copy_f32_kernel<<<blocks(B_ * H2_), 256, 0, stream>>>(h2f, out + o, B_ * H2_); o += B_ * H2_;
    copy_f32_kernel<<<blocks(B_ * H2_), 256, 0, stream>>>(c2,  out + o, B_ * H2_); o += B_ * H2_;
    copy_f32_kernel<<<blocks(B_ * H3_), 256, 0, stream>>>(h3f, out + o, B_ * H3_); o += B_ * H3_;
    copy_f32_kernel<<<blocks(B_ * H3_), 256, 0, stream>>>(c3,  out + o, B_ * H3_); o += B_ * H3_;
}